// Round 1
// baseline (25.033 us; speedup 1.0000x reference)
//
#include <hip/hip_runtime.h>

// Problem constants: DIM=2, L=13 (n = 8192 rows), BATCH=2048 cols,
// Hadamard on wires {0,5,9} -> row-index bits {12,7,3}.
// out[r,c] = (1/(2*sqrt(2))) * sum_{s in {0,1}^3} (-1)^(popcnt(r_bits & s)) * x[r_s, c]
// Real M => real/imag parts transform independently; harness output is the
// real part (out_size == n*b float32).

#define NROWS   8192
#define NCOLS   2048
#define COLS4   (NCOLS / 4)          // 512 float4 per row
#define NBASE   (NROWS / 8)          // 1024 base rows (bits 12,7,3 clear)
#define SCALE   0.35355339059327373f // (1/sqrt(2))^3

// float4-unit strides for the three butterfly bits
#define D3   (8    * COLS4)   // bit 3  -> +8 rows
#define D7   (128  * COLS4)   // bit 7  -> +128 rows
#define D12  (4096 * COLS4)   // bit 12 -> +4096 rows

__global__ __launch_bounds__(256) void had3_kernel(const float4* __restrict__ in,
                                                   float4* __restrict__ out) {
    int t = blockIdx.x * blockDim.x + threadIdx.x;   // 0 .. NBASE*COLS4-1
    int c    = t & (COLS4 - 1);                      // float4 column index
    int base = t >> 9;                               // 0 .. 1023

    // Expand 10 free bits of `base` into row bits {0-2, 4-6, 8-11}
    int r0 = (base & 0x7) | ((base & 0x38) << 1) | ((base & 0x3C0) << 2);
    long long idx = (long long)r0 * COLS4 + c;

    float4 v0 = in[idx];
    float4 v1 = in[idx + D3];
    float4 v2 = in[idx + D7];
    float4 v3 = in[idx + D7 + D3];
    float4 v4 = in[idx + D12];
    float4 v5 = in[idx + D12 + D3];
    float4 v6 = in[idx + D12 + D7];
    float4 v7 = in[idx + D12 + D7 + D3];

    float4 o0, o1, o2, o3, o4, o5, o6, o7;

    #pragma unroll
    for (int k = 0; k < 4; ++k) {
        float a0 = (&v0.x)[k], a1 = (&v1.x)[k], a2 = (&v2.x)[k], a3 = (&v3.x)[k];
        float a4 = (&v4.x)[k], a5 = (&v5.x)[k], a6 = (&v6.x)[k], a7 = (&v7.x)[k];

        // stage 1: bit 3
        float t0 = a0 + a1, t1 = a0 - a1;
        float t2 = a2 + a3, t3 = a2 - a3;
        float t4 = a4 + a5, t5 = a4 - a5;
        float t6 = a6 + a7, t7 = a6 - a7;
        // stage 2: bit 7
        float u0 = t0 + t2, u2 = t0 - t2;
        float u1 = t1 + t3, u3 = t1 - t3;
        float u4 = t4 + t6, u6 = t4 - t6;
        float u5 = t5 + t7, u7 = t5 - t7;
        // stage 3: bit 12
        (&o0.x)[k] = (u0 + u4) * SCALE;
        (&o1.x)[k] = (u1 + u5) * SCALE;
        (&o2.x)[k] = (u2 + u6) * SCALE;
        (&o3.x)[k] = (u3 + u7) * SCALE;
        (&o4.x)[k] = (u0 - u4) * SCALE;
        (&o5.x)[k] = (u1 - u5) * SCALE;
        (&o6.x)[k] = (u2 - u6) * SCALE;
        (&o7.x)[k] = (u3 - u7) * SCALE;
    }

    out[idx]                 = o0;
    out[idx + D3]            = o1;
    out[idx + D7]            = o2;
    out[idx + D7 + D3]       = o3;
    out[idx + D12]           = o4;
    out[idx + D12 + D3]      = o5;
    out[idx + D12 + D7]      = o6;
    out[idx + D12 + D7 + D3] = o7;
}

extern "C" void kernel_launch(void* const* d_in, const int* in_sizes, int n_in,
                              void* d_out, int out_size, void* d_ws, size_t ws_size,
                              hipStream_t stream) {
    const float* xr = (const float*)d_in[0];
    const float* xi = (const float*)d_in[1];
    float* out = (float*)d_out;

    const int N = NROWS * NCOLS;               // 16,777,216 elements per part
    const int threads = 256;
    const int total   = NBASE * COLS4;         // 524,288 threads
    const int blocks  = total / threads;       // 2048

    // Real part (harness output is the complex64 -> float32 cast, i.e. real).
    had3_kernel<<<blocks, threads, 0, stream>>>((const float4*)xr, (float4*)out);

    // Defensive: if the harness actually wants both parts (concatenated flat),
    // transform the imaginary part into the second half.
    if (out_size >= 2 * N) {
        had3_kernel<<<blocks, threads, 0, stream>>>((const float4*)xi,
                                                    (float4*)(out + N));
    }
}